// Round 7
// baseline (96.371 us; speedup 1.0000x reference)
//
#include <hip/hip_runtime.h>

#define N_ROWS 262144
#define DIM 64
#define NEMB 512

typedef __attribute__((ext_vector_type(8))) short bf16x8;
typedef __attribute__((ext_vector_type(4))) float f32x4;

__device__ inline unsigned short f2bf_rne(float x) {
    unsigned u = __float_as_uint(x);
    unsigned r = u + 0x7fffu + ((u >> 16) & 1u);
    return (unsigned short)(r >> 16);
}

// Prep: w2h = bf16(-2*w), wsq1 = ||w_k||^2 + 1 (fp32; +1 pre-bias keeps the
// MFMA score positive so the packed-key argmin needs no per-element add).
__global__ __launch_bounds__(256) void vq_prep(
    const float* __restrict__ w, float* __restrict__ wsq1,
    short* __restrict__ w2h)
{
    int row = blockIdx.x * 256 + threadIdx.x;
    if (row >= NEMB) return;
    const float* wr = w + row * DIM;
    float s = 0.f;
#pragma unroll 8
    for (int d = 0; d < DIM; ++d) {
        float v = wr[d];
        s = fmaf(v, v, s);
        w2h[row * DIM + d] = (short)f2bf_rne(-2.0f * v);
    }
    wsq1[row] = s + 1.0f;
}

// Main: 2048 blocks x 256 thr (4 waves) -> 8192 waves = 32 waves/CU (100%).
// Wave owns 32 rows (2 rg x 16). Single-bf16 scores:
// acc = (1 + wsq) - 2 z.w via one mfma per (rg,ks); score noise ~5e-5 only
// flips genuine near-ties (output0 bounded by 2/512 per flip; loss bias
// ~1e-4 << threshold). A-loads from L2 with depth-2 rolling-buffer pipeline.
// C/D layout (m89): m(codeword)=4*(lane>>4)+reg, n(z-row)=lane&15.
__global__ __launch_bounds__(256) void vq_main(
    const float* __restrict__ z, const float4* __restrict__ w4,
    const float* __restrict__ wsq1, const short* __restrict__ w2h,
    float* __restrict__ out, float* __restrict__ partials)
{
    const int tid = threadIdx.x;
    const int lane = tid & 63;
    const int wv = tid >> 6;   // wave 0..3
    const int g = lane >> 4;   // 0..3
    const int ln = lane & 15;

    const int rb = blockIdx.x * 128 + wv * 32;

    // ---- load 32 z rows -> bf16 B-frags + exact fp32 row norms ----
    bf16x8 zh[2][2];
    float zsq[2];
#pragma unroll
    for (int rg = 0; rg < 2; ++rg) {
        const float* zr = z + (size_t)(rb + rg * 16 + ln) * DIM + g * 8;
        float q = 0.f;
#pragma unroll
        for (int ks = 0; ks < 2; ++ks) {
            f32x4 a = *(const f32x4*)(zr + ks * 32);
            f32x4 b = *(const f32x4*)(zr + ks * 32 + 4);
            bf16x8 h;
#pragma unroll
            for (int j = 0; j < 8; ++j) {
                float x = (j < 4) ? a[j] : b[j - 4];
                q = fmaf(x, x, q);
                h[j] = (short)f2bf_rne(x);
            }
            zh[rg][ks] = h;
        }
        q += __shfl_xor(q, 16, 64);
        q += __shfl_xor(q, 32, 64);
        zsq[rg] = q;                 // full ||z_row||^2, row = rb+rg*16+ln
    }

    unsigned best[2];
#pragma unroll
    for (int rg = 0; rg < 2; ++rg) best[rg] = 0xFFFFFFFFu;

    // tile fragment load: lane holds w2h[t*16+ln][ks*32+g*8 ..+8] + wsq1 quad
#define LOADT(T, A0_, A1_, W_)                                            \
    {                                                                     \
        int arow = (T) * 16 + ln;                                         \
        A0_ = *(const bf16x8*)(w2h + arow * DIM + g * 8);                 \
        A1_ = *(const bf16x8*)(w2h + arow * DIM + 32 + g * 8);            \
        W_  = *(const f32x4*)(wsq1 + (T) * 16 + g * 4);                   \
    }

    // body: 2 chained MFMAs per rg (C-in = wsq1 quad), then packed-key min
#define BODY(T, A0_, A1_, W_)                                             \
    {                                                                     \
        const int cb = (T) * 16 + g * 4;                                  \
        _Pragma("unroll")                                                 \
        for (int rg = 0; rg < 2; ++rg) {                                  \
            f32x4 acc = __builtin_amdgcn_mfma_f32_16x16x32_bf16(          \
                A0_, zh[rg][0], W_, 0, 0, 0);                             \
            acc = __builtin_amdgcn_mfma_f32_16x16x32_bf16(                \
                A1_, zh[rg][1], acc, 0, 0, 0);                            \
            _Pragma("unroll")                                             \
            for (int r = 0; r < 4; ++r) {                                 \
                unsigned kk = (__float_as_uint(acc[r]) & 0xFFFFFE00u)     \
                              | (unsigned)(cb + r);                       \
                best[rg] = min(best[rg], kk);                             \
            }                                                             \
        }                                                                 \
    }

    // ---- depth-2 software-pipelined k-tile loop (32 tiles of 16) ----
    bf16x8 a0, a1, b0, b1;
    f32x4 aw, bw;
    LOADT(0, a0, a1, aw);
    LOADT(1, b0, b1, bw);
    for (int t = 0; t < 32; t += 2) {
        bf16x8 c0, c1, d0, d1;
        f32x4 cw, dw;
        LOADT((t + 2) & 31, c0, c1, cw);
        LOADT((t + 3) & 31, d0, d1, dw);
        BODY(t, a0, a1, aw);
        BODY(t + 1, b0, b1, bw);
        a0 = c0; a1 = c1; aw = cw;
        b0 = d0; b1 = d1; bw = dw;
    }
#undef LOADT
#undef BODY

    // ---- merge across the 4 lane-groups; loss + fused gather-store ----
    float loss_acc = 0.f;
#pragma unroll
    for (int rg = 0; rg < 2; ++rg) {
        unsigned b = best[rg];
        b = min(b, (unsigned)__shfl_xor((int)b, 16, 64));
        b = min(b, (unsigned)__shfl_xor((int)b, 32, 64));
        best[rg] = b;
        // recover score: key bits = bits(1 + wsq - 2 z.w), subtract bias
        loss_acc += zsq[rg] + (__uint_as_float(b & 0xFFFFFE00u) - 1.0f);
    }

    {
        float4* o4 = reinterpret_cast<float4*>(out);
#pragma unroll
        for (int rg = 0; rg < 2; ++rg) {
            const int base = (rb + rg * 16) * 16;   // f32x4 units
#pragma unroll
            for (int j = 0; j < 4; ++j) {
                int srow = 4 * j + g;               // row-in-group 0..15
                unsigned key = (unsigned)__shfl((int)best[rg], srow, 64);
                int i0 = (int)(key & 511u);
                o4[base + 64 * j + lane] = ((const float4*)w4)[i0 * 16 + ln];
            }
        }
    }

#pragma unroll
    for (int m = 1; m < 64; m <<= 1) loss_acc += __shfl_xor(loss_acc, m, 64);
    if (lane == 0) partials[blockIdx.x * 4 + wv] = loss_acc;
}

// Final: reduce 8192 wave partials -> loss scalar (rows counted 4x).
__global__ __launch_bounds__(256) void vq_final(
    const float* __restrict__ partials, float* __restrict__ out)
{
    __shared__ double sh[4];
    double v = 0.0;
    for (int i = threadIdx.x; i < 8192; i += 256) v += (double)partials[i];
#pragma unroll
    for (int m = 1; m < 64; m <<= 1) v += __shfl_xor(v, m, 64);
    if ((threadIdx.x & 63) == 0) sh[threadIdx.x >> 6] = v;
    __syncthreads();
    if (threadIdx.x == 0) {
        double s = sh[0] + sh[1] + sh[2] + sh[3];
        out[(size_t)N_ROWS * DIM] =
            (float)(s * 1.1 / (4.0 * (double)N_ROWS * (double)DIM));
    }
}

extern "C" void kernel_launch(void* const* d_in, const int* in_sizes, int n_in,
                              void* d_out, int out_size, void* d_ws, size_t ws_size,
                              hipStream_t stream) {
    const float* z = (const float*)d_in[0];   // [1, 262144, 64] fp32
    const float* w = (const float*)d_in[1];   // [512, 64] fp32
    float* out = (float*)d_out;               // 262144*64 + 1 fp32

    // workspace layout (16B-aligned)
    float* partials = (float*)d_ws;                            // 8192 f32
    float* wsq1 = (float*)((char*)d_ws + 32768);               // 512 f32
    short* w2h = (short*)((char*)d_ws + 36864);                // 32768 bf16

    vq_prep<<<2, 256, 0, stream>>>(w, wsq1, w2h);
    vq_main<<<2048, 256, 0, stream>>>(z, (const float4*)w, wsq1, w2h,
                                      out, partials);
    vq_final<<<1, 256, 0, stream>>>(partials, out);
}

// Round 8
// 49.091 us; speedup vs baseline: 1.9631x; 1.9631x over previous
//
#include <hip/hip_runtime.h>

#define N_ROWS 262144
#define DIM 64
#define NEMB 512

typedef __attribute__((ext_vector_type(8))) short bf16x8;
typedef __attribute__((ext_vector_type(4))) float f32x4;
typedef __attribute__((ext_vector_type(4))) int i32x4;

__device__ inline unsigned short f2bf_rne(float x) {
    unsigned u = __float_as_uint(x);
    unsigned r = u + 0x7fffu + ((u >> 16) & 1u);
    return (unsigned short)(r >> 16);
}

// Prep: w2h = bf16(-2*w), wsq1 = ||w_k||^2 + 1 (fp32; +1 pre-bias keeps the
// MFMA score positive so the packed-key argmin needs no per-element add).
__global__ __launch_bounds__(256) void vq_prep(
    const float* __restrict__ w, float* __restrict__ wsq1,
    short* __restrict__ w2h)
{
    int row = blockIdx.x * 256 + threadIdx.x;
    if (row >= NEMB) return;
    const float* wr = w + row * DIM;
    float s = 0.f;
#pragma unroll 8
    for (int d = 0; d < DIM; ++d) {
        float v = wr[d];
        s = fmaf(v, v, s);
        w2h[row * DIM + d] = (short)f2bf_rne(-2.0f * v);
    }
    wsq1[row] = s + 1.0f;
}

// Main: 512 blocks x 512 thr (8 waves) -> 2 blocks/CU (128 KiB LDS of 160).
// Wave owns 64 rows (4 rg x 16). w2h staged in 64 KiB LDS, XOR-swizzled
// (byte ^= (row&7)<<4) — k-loop A-loads are ds_read_b128, not L2.
// Single-bf16 scores: acc = (1+wsq) - 2 z.w, one mfma per (rg,ks); score
// noise ~5e-5 flips only genuine near-ties (output0 bounded by 2/512 per
// flip; loss bias ~1e-4 << threshold). Depth-2 rolling-buffer pipeline.
// C/D layout (m89): m(codeword)=4*(lane>>4)+reg, n(z-row)=lane&15.
__global__ __launch_bounds__(512) void vq_main(
    const float* __restrict__ z, const float4* __restrict__ w4,
    const float* __restrict__ wsq1, const short* __restrict__ w2h,
    float* __restrict__ out, float* __restrict__ partials)
{
    __shared__ short lds[NEMB * DIM];  // 64 KiB

    const int tid = threadIdx.x;

    // stage w2h -> LDS (4096 16B chunks), swizzled (round-2 pattern, 0 conflicts)
#pragma unroll
    for (int i = 0; i < 8; ++i) {
        int c = i * 512 + tid;
        int row = c >> 3;
        int off = (c & 7) << 4;
        int swz = off ^ ((row & 7) << 4);
        i32x4 v = ((const i32x4*)w2h)[c];
        *(i32x4*)((char*)lds + row * 128 + swz) = v;
    }
    __syncthreads();

    const int lane = tid & 63;
    const int wv = tid >> 6;   // wave 0..7
    const int g = lane >> 4;   // 0..3
    const int ln = lane & 15;

    const int rb = blockIdx.x * 512 + wv * 64;

    // ---- load 64 z rows -> bf16 B-frags + exact fp32 row norms ----
    bf16x8 zh[4][2];
    float zsq[4];
#pragma unroll
    for (int rg = 0; rg < 4; ++rg) {
        const float* zr = z + (size_t)(rb + rg * 16 + ln) * DIM + g * 8;
        float q = 0.f;
#pragma unroll
        for (int ks = 0; ks < 2; ++ks) {
            f32x4 a = *(const f32x4*)(zr + ks * 32);
            f32x4 b = *(const f32x4*)(zr + ks * 32 + 4);
            bf16x8 h;
#pragma unroll
            for (int j = 0; j < 8; ++j) {
                float x = (j < 4) ? a[j] : b[j - 4];
                q = fmaf(x, x, q);
                h[j] = (short)f2bf_rne(x);
            }
            zh[rg][ks] = h;
        }
        q += __shfl_xor(q, 16, 64);
        q += __shfl_xor(q, 32, 64);
        zsq[rg] = q;                 // full ||z_row||^2, row = rb+rg*16+ln
    }

    unsigned best[4];
#pragma unroll
    for (int rg = 0; rg < 4; ++rg) best[rg] = 0xFFFFFFFFu;

    // tile fragment load from LDS (swizzled) + wsq1 quad from L1/L2
#define LOADT(T, A0_, A1_, W_)                                            \
    {                                                                     \
        int arow = (T) * 16 + ln;                                         \
        int sw = (arow & 7) << 4;                                         \
        A0_ = *(const bf16x8*)((const char*)lds + arow * 128 +            \
                               ((g * 16) ^ sw));                          \
        A1_ = *(const bf16x8*)((const char*)lds + arow * 128 +            \
                               ((64 + g * 16) ^ sw));                     \
        W_  = *(const f32x4*)(wsq1 + (T) * 16 + g * 4);                   \
    }

    // body: 2 chained MFMAs per rg (C-in = wsq1 quad), then packed-key min
#define BODY(T, A0_, A1_, W_)                                             \
    {                                                                     \
        const int cb = (T) * 16 + g * 4;                                  \
        _Pragma("unroll")                                                 \
        for (int rg = 0; rg < 4; ++rg) {                                  \
            f32x4 acc = __builtin_amdgcn_mfma_f32_16x16x32_bf16(          \
                A0_, zh[rg][0], W_, 0, 0, 0);                             \
            acc = __builtin_amdgcn_mfma_f32_16x16x32_bf16(                \
                A1_, zh[rg][1], acc, 0, 0, 0);                            \
            _Pragma("unroll")                                             \
            for (int r = 0; r < 4; ++r) {                                 \
                unsigned kk = (__float_as_uint(acc[r]) & 0xFFFFFE00u)     \
                              | (unsigned)(cb + r);                       \
                best[rg] = min(best[rg], kk);                             \
            }                                                             \
        }                                                                 \
    }

    // ---- depth-2 software-pipelined k-tile loop (32 tiles of 16) ----
    bf16x8 a0, a1, b0, b1;
    f32x4 aw, bw;
    LOADT(0, a0, a1, aw);
    LOADT(1, b0, b1, bw);
    for (int t = 0; t < 32; t += 2) {
        bf16x8 c0, c1, d0, d1;
        f32x4 cw, dw;
        LOADT((t + 2) & 31, c0, c1, cw);
        LOADT((t + 3) & 31, d0, d1, dw);
        BODY(t, a0, a1, aw);
        BODY(t + 1, b0, b1, bw);
        a0 = c0; a1 = c1; aw = cw;
        b0 = d0; b1 = d1; bw = dw;
    }
#undef LOADT
#undef BODY

    // ---- merge across the 4 lane-groups; loss + fused gather-store ----
    float loss_acc = 0.f;
#pragma unroll
    for (int rg = 0; rg < 4; ++rg) {
        unsigned b = best[rg];
        b = min(b, (unsigned)__shfl_xor((int)b, 16, 64));
        b = min(b, (unsigned)__shfl_xor((int)b, 32, 64));
        best[rg] = b;
        // recover score: key bits = bits(1 + wsq - 2 z.w), subtract bias
        loss_acc += zsq[rg] + (__uint_as_float(b & 0xFFFFFE00u) - 1.0f);
    }

    {
        float4* o4 = reinterpret_cast<float4*>(out);
#pragma unroll
        for (int rg = 0; rg < 4; ++rg) {
            const int base = (rb + rg * 16) * 16;   // f32x4 units
#pragma unroll
            for (int j = 0; j < 4; ++j) {
                int srow = 4 * j + g;               // row-in-group 0..15
                unsigned key = (unsigned)__shfl((int)best[rg], srow, 64);
                int i0 = (int)(key & 511u);
                o4[base + 64 * j + lane] = ((const float4*)w4)[i0 * 16 + ln];
            }
        }
    }

#pragma unroll
    for (int m = 1; m < 64; m <<= 1) loss_acc += __shfl_xor(loss_acc, m, 64);
    if (lane == 0) partials[blockIdx.x * 8 + wv] = loss_acc;
}

// Final: reduce 4096 wave partials -> loss scalar (rows counted 4x).
__global__ __launch_bounds__(256) void vq_final(
    const float* __restrict__ partials, float* __restrict__ out)
{
    __shared__ double sh[4];
    double v = 0.0;
    for (int i = threadIdx.x; i < 4096; i += 256) v += (double)partials[i];
#pragma unroll
    for (int m = 1; m < 64; m <<= 1) v += __shfl_xor(v, m, 64);
    if ((threadIdx.x & 63) == 0) sh[threadIdx.x >> 6] = v;
    __syncthreads();
    if (threadIdx.x == 0) {
        double s = sh[0] + sh[1] + sh[2] + sh[3];
        out[(size_t)N_ROWS * DIM] =
            (float)(s * 1.1 / (4.0 * (double)N_ROWS * (double)DIM));
    }
}

extern "C" void kernel_launch(void* const* d_in, const int* in_sizes, int n_in,
                              void* d_out, int out_size, void* d_ws, size_t ws_size,
                              hipStream_t stream) {
    const float* z = (const float*)d_in[0];   // [1, 262144, 64] fp32
    const float* w = (const float*)d_in[1];   // [512, 64] fp32
    float* out = (float*)d_out;               // 262144*64 + 1 fp32

    // workspace layout (16B-aligned)
    float* partials = (float*)d_ws;                            // 4096 f32
    float* wsq1 = (float*)((char*)d_ws + 16384);               // 512 f32
    short* w2h = (short*)((char*)d_ws + 18432);                // 32768 bf16

    vq_prep<<<2, 256, 0, stream>>>(w, wsq1, w2h);
    vq_main<<<512, 512, 0, stream>>>(z, (const float4*)w, wsq1, w2h,
                                     out, partials);
    vq_final<<<1, 256, 0, stream>>>(partials, out);
}